// Round 4
// baseline (3866.334 us; speedup 1.0000x reference)
//
#include <hip/hip_runtime.h>
#include <stdint.h>

// ---------------------------------------------------------------------------
#define LSEQ 768
#define DM   256
#define NH   8
#define DK   32
#define DFF  1024
#define NLAYER 8
#define NDD  1535
// ---------------------------------------------------------------------------

typedef __attribute__((ext_vector_type(8))) short  bf16x8;
typedef __attribute__((ext_vector_type(4))) float  f32x4;

__device__ __forceinline__ unsigned short f2bf(float f) {
  unsigned u = __float_as_uint(f);
  u += 0x7fffu + ((u >> 16) & 1u);       // RNE
  return (unsigned short)(u >> 16);
}

// ---------------------------------------------------------------------------
// Coherent (cross-XCD) access helpers: agent-scope relaxed atomics emit
// sc1-tagged global ops that bypass the per-XCD L2 and are coherent at the
// Infinity Cache. Used for all tensors written in one grid-phase and read in
// a later one. No fences needed: __syncthreads' vmcnt(0) drains the stores.
__device__ __forceinline__ float2 ld2(const float* p) {
  union { unsigned long long u; float2 f; } c;
  c.u = __hip_atomic_load((unsigned long long*)(uintptr_t)p,
                          __ATOMIC_RELAXED, __HIP_MEMORY_SCOPE_AGENT);
  return c.f;
}
__device__ __forceinline__ void st2(float* p, float2 f) {
  union { float2 f; unsigned long long u; } c; c.f = f;
  __hip_atomic_store((unsigned long long*)p, c.u,
                     __ATOMIC_RELAXED, __HIP_MEMORY_SCOPE_AGENT);
}
__device__ __forceinline__ float ld1(const float* p) {
  union { unsigned u; float f; } c;
  c.u = __hip_atomic_load((unsigned*)(uintptr_t)p,
                          __ATOMIC_RELAXED, __HIP_MEMORY_SCOPE_AGENT);
  return c.f;
}
__device__ __forceinline__ int ld1i(const int* p) {
  return (int)__hip_atomic_load((unsigned*)(uintptr_t)p,
                                __ATOMIC_RELAXED, __HIP_MEMORY_SCOPE_AGENT);
}
__device__ __forceinline__ void st1i(int* p, int v) {
  __hip_atomic_store((unsigned*)p, (unsigned)v,
                     __ATOMIC_RELAXED, __HIP_MEMORY_SCOPE_AGENT);
}
__device__ __forceinline__ float4 ld4c(const float* p) {
  float2 a = ld2(p), b = ld2(p + 2);
  return make_float4(a.x, a.y, b.x, b.y);
}
__device__ __forceinline__ void st4c(float* p, float4 v) {
  st2(p, make_float2(v.x, v.y));
  st2(p + 2, make_float2(v.z, v.w));
}

// ---------------------------------------------------------------------------
// Grid barrier WITHOUT device fence (the round-3 killer). Correctness:
// all cross-phase data uses sc1 ops (above); __syncthreads emits
// s_waitcnt vmcnt(0) per wave before s_barrier, so when block 0's lane
// signals, every store of this block is already acked at the L3.
__device__ __forceinline__ void grid_bar(unsigned int* bar, unsigned int tgt) {
  __syncthreads();
  if (threadIdx.x == 0) {
    __hip_atomic_fetch_add(bar, 1u, __ATOMIC_RELAXED, __HIP_MEMORY_SCOPE_AGENT);
    while (__hip_atomic_load(bar, __ATOMIC_RELAXED, __HIP_MEMORY_SCOPE_AGENT) < tgt)
      __builtin_amdgcn_s_sleep(4);
  }
  __syncthreads();
}

// ---------------------------------------------------------------------------
// GEMM tile: 64x64, BK=32, register-prefetch double-buffered LDS.
// A/C/res = activations (coherent); B/bias/lns/lnb = weights (plain cached).
// GATHER: A rows gathered from plain gsrc via coherent lut.
// ATOMIC: accumulate into C with device-scope atomicAdd (split-K).
// COC: coherent C stores (consumed by a later phase); else plain (consumed
// by the next dispatch only).
template <int LN, int GELU, int RES, int GATHER, int ATOMIC, int COC>
__device__ void gemm_tile(const float* A, int lda,
                          const float* gsrc, const int* gather,
                          const float* B, const float* bias, float* C,
                          const float* res, const float* lns, const float* lnb,
                          int M, int K, int N, int m0, int n0, char* smc) {
  float (*As)[32][68] = (float (*)[32][68])smc;
  float (*Bs)[32][68] = (float (*)[32][68])(smc + 17408);
  float (*stat)[2]    = (float (*)[2])(smc + 34816);
  float (*red)[8]     = (float (*)[8])(smc + 35328);

  int t = threadIdx.x;
  int arow = t >> 2, akq = (t & 3) * 8;
  int mg = m0 + arow;
  int mgc = mg < M ? mg : M - 1;
  const float* Ar = GATHER ? (gsrc + (size_t)ld1i(&gather[mgc]) * K)
                           : (A + (size_t)mgc * lda);
  float mean = 0.f, rstd = 0.f;
  if (LN) {
    int lq = t & 3;
    float s = 0.f, s2 = 0.f;
    const float* p = Ar + lq * 64;
    #pragma unroll
    for (int c = 0; c < 64; c += 4) {
      float4 v = ld4c(p + c);
      s  += v.x + v.y + v.z + v.w;
      s2 += v.x * v.x + v.y * v.y + v.z * v.z + v.w * v.w;
    }
    red[arow][lq] = s; red[arow][lq + 4] = s2;
    __syncthreads();
    if (lq == 0) {
      float sm = red[arow][0] + red[arow][1] + red[arow][2] + red[arow][3];
      float sq = red[arow][4] + red[arow][5] + red[arow][6] + red[arow][7];
      float m = sm * (1.f / 256.f);
      float v = sq * (1.f / 256.f) - m * m;
      stat[arow][0] = m;
      stat[arow][1] = rsqrtf(v + 1e-5f);
    }
    __syncthreads();
    mean = stat[arow][0]; rstd = stat[arow][1];
  }

  int bkr = t >> 3, bn8 = (t & 7) * 8;
  int ty = t >> 4, tx = t & 15;
  float acc[4][4] = {};
  int nk = K >> 5;
  float4 a0, a1, b0, b1;

  {
    a0 = GATHER ? *(const float4*)(Ar + akq)     : ld4c(Ar + akq);
    a1 = GATHER ? *(const float4*)(Ar + akq + 4) : ld4c(Ar + akq + 4);
    if (LN) {
      float4 ls0 = *(const float4*)(lns + akq), ls1 = *(const float4*)(lns + akq + 4);
      float4 lb0 = *(const float4*)(lnb + akq), lb1 = *(const float4*)(lnb + akq + 4);
      a0.x=(a0.x-mean)*rstd*ls0.x+lb0.x; a0.y=(a0.y-mean)*rstd*ls0.y+lb0.y;
      a0.z=(a0.z-mean)*rstd*ls0.z+lb0.z; a0.w=(a0.w-mean)*rstd*ls0.w+lb0.w;
      a1.x=(a1.x-mean)*rstd*ls1.x+lb1.x; a1.y=(a1.y-mean)*rstd*ls1.y+lb1.y;
      a1.z=(a1.z-mean)*rstd*ls1.z+lb1.z; a1.w=(a1.w-mean)*rstd*ls1.w+lb1.w;
    }
    b0 = *(const float4*)(B + (size_t)bkr * N + n0 + bn8);
    b1 = *(const float4*)(B + (size_t)bkr * N + n0 + bn8 + 4);
    As[0][akq+0][arow]=a0.x; As[0][akq+1][arow]=a0.y; As[0][akq+2][arow]=a0.z; As[0][akq+3][arow]=a0.w;
    As[0][akq+4][arow]=a1.x; As[0][akq+5][arow]=a1.y; As[0][akq+6][arow]=a1.z; As[0][akq+7][arow]=a1.w;
    *(float4*)&Bs[0][bkr][bn8] = b0;
    *(float4*)&Bs[0][bkr][bn8+4] = b1;
  }
  __syncthreads();

  for (int kt = 0; kt < nk; ++kt) {
    int cur = kt & 1;
    if (kt + 1 < nk) {
      int k0 = (kt + 1) << 5;
      a0 = GATHER ? *(const float4*)(Ar + k0 + akq)     : ld4c(Ar + k0 + akq);
      a1 = GATHER ? *(const float4*)(Ar + k0 + akq + 4) : ld4c(Ar + k0 + akq + 4);
      if (LN) {
        float4 ls0 = *(const float4*)(lns + k0 + akq), ls1 = *(const float4*)(lns + k0 + akq + 4);
        float4 lb0 = *(const float4*)(lnb + k0 + akq), lb1 = *(const float4*)(lnb + k0 + akq + 4);
        a0.x=(a0.x-mean)*rstd*ls0.x+lb0.x; a0.y=(a0.y-mean)*rstd*ls0.y+lb0.y;
        a0.z=(a0.z-mean)*rstd*ls0.z+lb0.z; a0.w=(a0.w-mean)*rstd*ls0.w+lb0.w;
        a1.x=(a1.x-mean)*rstd*ls1.x+lb1.x; a1.y=(a1.y-mean)*rstd*ls1.y+lb1.y;
        a1.z=(a1.z-mean)*rstd*ls1.z+lb1.z; a1.w=(a1.w-mean)*rstd*ls1.w+lb1.w;
      }
      b0 = *(const float4*)(B + (size_t)(k0 + bkr) * N + n0 + bn8);
      b1 = *(const float4*)(B + (size_t)(k0 + bkr) * N + n0 + bn8 + 4);
    }
    #pragma unroll
    for (int kk = 0; kk < 32; ++kk) {
      float4 a = *(float4*)&As[cur][kk][ty * 4];
      float4 b = *(float4*)&Bs[cur][kk][tx * 4];
      acc[0][0]=fmaf(a.x,b.x,acc[0][0]); acc[0][1]=fmaf(a.x,b.y,acc[0][1]);
      acc[0][2]=fmaf(a.x,b.z,acc[0][2]); acc[0][3]=fmaf(a.x,b.w,acc[0][3]);
      acc[1][0]=fmaf(a.y,b.x,acc[1][0]); acc[1][1]=fmaf(a.y,b.y,acc[1][1]);
      acc[1][2]=fmaf(a.y,b.z,acc[1][2]); acc[1][3]=fmaf(a.y,b.w,acc[1][3]);
      acc[2][0]=fmaf(a.z,b.x,acc[2][0]); acc[2][1]=fmaf(a.z,b.y,acc[2][1]);
      acc[2][2]=fmaf(a.z,b.z,acc[2][2]); acc[2][3]=fmaf(a.z,b.w,acc[2][3]);
      acc[3][0]=fmaf(a.w,b.x,acc[3][0]); acc[3][1]=fmaf(a.w,b.y,acc[3][1]);
      acc[3][2]=fmaf(a.w,b.z,acc[3][2]); acc[3][3]=fmaf(a.w,b.w,acc[3][3]);
    }
    if (kt + 1 < nk) {
      int nxt = cur ^ 1;
      As[nxt][akq+0][arow]=a0.x; As[nxt][akq+1][arow]=a0.y; As[nxt][akq+2][arow]=a0.z; As[nxt][akq+3][arow]=a0.w;
      As[nxt][akq+4][arow]=a1.x; As[nxt][akq+5][arow]=a1.y; As[nxt][akq+6][arow]=a1.z; As[nxt][akq+7][arow]=a1.w;
      *(float4*)&Bs[nxt][bkr][bn8] = b0;
      *(float4*)&Bs[nxt][bkr][bn8+4] = b1;
    }
    __syncthreads();
  }

  #pragma unroll
  for (int u = 0; u < 4; ++u) {
    int m = m0 + ty * 4 + u;
    if (m < M) {
      int n = n0 + tx * 4;
      float4 val = make_float4(acc[u][0], acc[u][1], acc[u][2], acc[u][3]);
      if (bias) {
        float4 bv = *(const float4*)(bias + n);
        val.x += bv.x; val.y += bv.y; val.z += bv.z; val.w += bv.w;
      }
      if (GELU) {
        val.x = 0.5f * val.x * (1.f + erff(val.x * 0.70710678118654752f));
        val.y = 0.5f * val.y * (1.f + erff(val.y * 0.70710678118654752f));
        val.z = 0.5f * val.z * (1.f + erff(val.z * 0.70710678118654752f));
        val.w = 0.5f * val.w * (1.f + erff(val.w * 0.70710678118654752f));
      }
      if (RES) {
        float4 r = ld4c(res + (size_t)m * N + n);
        val.x += r.x; val.y += r.y; val.z += r.z; val.w += r.w;
      }
      if (ATOMIC) {
        atomicAdd(&C[(size_t)m * N + n + 0], val.x);
        atomicAdd(&C[(size_t)m * N + n + 1], val.y);
        atomicAdd(&C[(size_t)m * N + n + 2], val.z);
        atomicAdd(&C[(size_t)m * N + n + 3], val.w);
      } else if (COC) {
        st4c(C + (size_t)m * N + n, val);
      } else {
        *(float4*)(C + (size_t)m * N + n) = val;
      }
    }
  }
}

// ---------------------------------------------------------------------------
// Attention task: 16 query rows x 1 head. q/o row-sliced (coherent), k/v
// all-to-all (coherent), abias staged to LDS once per task.
// LDS: S[16][776] @0 (49664), red @49664 (1024), mrow @50688, linv @50752,
// pr @50816 (9216), bias_s @60032 (3136) -> 63168.
__device__ void attn_task(const float* q, const float* k, const float* v,
                          const float* abias, float* o, int i0, int h, char* smc) {
  float* S = (float*)smc;
  float (*red)[16] = (float (*)[16])(smc + 49664);
  float* mrow = (float*)(smc + 50688);
  float* linv = (float*)(smc + 50752);
  float* pr   = (float*)(smc + 50816);
  float* bias_s = (float*)(smc + 60032);   // 783 entries, idx = ti + 767 - j

  int hc = h * DK;
  int t = threadIdx.x;
  int ti = t >> 4, tj = t & 15;

  for (int u = t; u < 783; u += 256)
    bias_s[u] = ld1(&abias[(size_t)(i0 + u) * 8 + h]);

  float qr[32];
  {
    const float* qp = q + (size_t)(i0 + ti) * DM + hc;
    const float inv = 0.17677669529663687f;   // 1/sqrt(32)
    #pragma unroll
    for (int c = 0; c < 32; c += 4) {
      float4 v4 = ld4c(qp + c);
      qr[c+0] = v4.x * inv; qr[c+1] = v4.y * inv;
      qr[c+2] = v4.z * inv; qr[c+3] = v4.w * inv;
    }
  }
  __syncthreads();   // bias_s ready

  float mx = -1e30f;
  for (int jc = 0; jc < 48; ++jc) {
    int j = jc * 16 + tj;
    const float* kr = k + (size_t)j * DM + hc;
    float acc = 0.f;
    #pragma unroll
    for (int c = 0; c < 32; c += 4) {
      float4 kv = ld4c(kr + c);
      acc = fmaf(qr[c+0], kv.x, acc);
      acc = fmaf(qr[c+1], kv.y, acc);
      acc = fmaf(qr[c+2], kv.z, acc);
      acc = fmaf(qr[c+3], kv.w, acc);
    }
    acc += bias_s[ti + 767 - j];
    S[ti * 776 + j] = acc;
    mx = fmaxf(mx, acc);
  }
  red[ti][tj] = mx;
  __syncthreads();
  if (tj == 0) {
    float m2 = red[ti][0];
    #pragma unroll
    for (int u = 1; u < 16; ++u) m2 = fmaxf(m2, red[ti][u]);
    mrow[ti] = m2;
  }
  __syncthreads();
  float m2 = mrow[ti];
  float sum = 0.f;
  for (int jc = 0; jc < 48; ++jc) {
    int j = jc * 16 + tj;
    float e = __expf(S[ti * 776 + j] - m2);
    S[ti * 776 + j] = e;
    sum += e;
  }
  red[ti][tj] = sum;
  __syncthreads();
  if (tj == 0) {
    float s2 = 0.f;
    #pragma unroll
    for (int u = 0; u < 16; ++u) s2 += red[ti][u];
    linv[ti] = 1.f / s2;
  }
  __syncthreads();

  {
    int wv = t >> 6, l = t & 63;
    int c4 = (l & 7) * 4;
    int ib = l >> 3;
    float a00=0,a01=0,a02=0,a03=0, a10=0,a11=0,a12=0,a13=0;
    const float* vp = v + hc + c4;
    int jbeg = wv * 192;
    for (int j = jbeg; j < jbeg + 192; j += 4) {
      float4 s0 = *(float4*)&S[ib * 776 + j];
      float4 s1 = *(float4*)&S[(ib + 8) * 776 + j];
      const float* vj = vp + (size_t)j * DM;
      float4 v0 = ld4c(vj);
      float4 v1 = ld4c(vj + DM);
      float4 v2 = ld4c(vj + 2 * DM);
      float4 v3 = ld4c(vj + 3 * DM);
      a00=fmaf(s0.x,v0.x,a00); a01=fmaf(s0.x,v0.y,a01); a02=fmaf(s0.x,v0.z,a02); a03=fmaf(s0.x,v0.w,a03);
      a10=fmaf(s1.x,v0.x,a10); a11=fmaf(s1.x,v0.y,a11); a12=fmaf(s1.x,v0.z,a12); a13=fmaf(s1.x,v0.w,a13);
      a00=fmaf(s0.y,v1.x,a00); a01=fmaf(s0.y,v1.y,a01); a02=fmaf(s0.y,v1.z,a02); a03=fmaf(s0.y,v1.w,a03);
      a10=fmaf(s1.y,v1.x,a10); a11=fmaf(s1.y,v1.y,a11); a12=fmaf(s1.y,v1.z,a12); a13=fmaf(s1.y,v1.w,a13);
      a00=fmaf(s0.z,v2.x,a00); a01=fmaf(s0.z,v2.y,a01); a02=fmaf(s0.z,v2.z,a02); a03=fmaf(s0.z,v2.w,a03);
      a10=fmaf(s1.z,v2.x,a10); a11=fmaf(s1.z,v2.y,a11); a12=fmaf(s1.z,v2.z,a12); a13=fmaf(s1.z,v2.w,a13);
      a00=fmaf(s0.w,v3.x,a00); a01=fmaf(s0.w,v3.y,a01); a02=fmaf(s0.w,v3.z,a02); a03=fmaf(s0.w,v3.w,a03);
      a10=fmaf(s1.w,v3.x,a10); a11=fmaf(s1.w,v3.y,a11); a12=fmaf(s1.w,v3.z,a12); a13=fmaf(s1.w,v3.w,a13);
    }
    pr[(ib * 4 + wv) * 36 + c4 + 0] = a00;
    pr[(ib * 4 + wv) * 36 + c4 + 1] = a01;
    pr[(ib * 4 + wv) * 36 + c4 + 2] = a02;
    pr[(ib * 4 + wv) * 36 + c4 + 3] = a03;
    pr[((ib + 8) * 4 + wv) * 36 + c4 + 0] = a10;
    pr[((ib + 8) * 4 + wv) * 36 + c4 + 1] = a11;
    pr[((ib + 8) * 4 + wv) * 36 + c4 + 2] = a12;
    pr[((ib + 8) * 4 + wv) * 36 + c4 + 3] = a13;
  }
  __syncthreads();
  {
    int idx = t * 2;
    int i = idx >> 5, c = idx & 31;
    float s0 = pr[(i*4+0)*36 + c] + pr[(i*4+1)*36 + c]
             + pr[(i*4+2)*36 + c] + pr[(i*4+3)*36 + c];
    float s1 = pr[(i*4+0)*36 + c+1] + pr[(i*4+1)*36 + c+1]
             + pr[(i*4+2)*36 + c+1] + pr[(i*4+3)*36 + c+1];
    st2(o + (size_t)(i0 + i) * DM + hc + c,
        make_float2(s0 * linv[i], s1 * linv[i]));
  }
}

// ---------------------------------------------------------------------------
// Persistent megakernel: grid=512 (2 blocks/CU), 41 fence-free barriers.
__global__ __launch_bounds__(256, 2) void k_stack(
    const int* __restrict__ seq, const float* __restrict__ tok_emb,
    const float* __restrict__ rp_emb,
    const float* __restrict__ wq, const float* __restrict__ wk,
    const float* __restrict__ wv, const float* __restrict__ wo_,
    const float* __restrict__ ln1_s, const float* __restrict__ ln1_b,
    const float* __restrict__ ln2_s, const float* __restrict__ ln2_b,
    const float* __restrict__ ffn_w1, const float* __restrict__ ffn_b1,
    const float* __restrict__ ffn_w2, const float* __restrict__ ffn_b2,
    const float* __restrict__ lnf_s, const float* __restrict__ lnf_b,
    const float* __restrict__ pair_q_w, const float* __restrict__ pair_q_b,
    const float* __restrict__ pair_k_w, const float* __restrict__ pair_k_b,
    const float* __restrict__ pair_rp, const float* __restrict__ cls_w1,
    const float* __restrict__ cls_b1,
    float* x, float* q, float* k, float* v, float* o, float* f1,
    float* pq, float* pk, float* RB, unsigned short* W1p,
    int* lut, float* abias, unsigned int* bar) {
  __shared__ __align__(16) char sm[63168];
  int bid = blockIdx.x, t = threadIdx.x;
  unsigned int gen = 0;
  int gid = bid * 256 + t;

  // ---- P0 ----
  if (gid < NDD) {
    int rel = gid - 767;
    int ret = rel < 0 ? 32 : 0;
    int arp = rel < 0 ? -rel : rel;
    int bk;
    if (arp < 16) {
      bk = ret + arp;
    } else {
      const float lr = 2.772588722239781f;   // float(np.log(16))
      float val = logf((float)arp * 0.0625f) / lr * 16.0f;
      int vi = 16 + (int)val;
      bk = ret + (vi < 31 ? vi : 31);
    }
    st1i(&lut[gid], bk);
    #pragma unroll
    for (int h = 0; h < NH; h += 2)
      st2(&abias[gid * 8 + h], make_float2(rp_emb[bk * 8 + h], rp_emb[bk * 8 + h + 1]));
  }
  if (gid < 49152) {   // embed: one float4 group
    int row = gid >> 6, c = (gid & 63) * 4;
    st4c(x + (size_t)row * DM + c,
         *(const float4*)(tok_emb + (size_t)seq[row] * DM + c));
  }
  if (gid < 32768) {   // W1p pack: 2 bf16 per thread (plain; read by k_pair)
    int id = gid * 2;
    int e = id & 7, lane = (id >> 3) & 63, g = (id >> 9) & 15, kc = id >> 13;
    int kg = kc * 32 + (lane >> 4) * 8 + e;
    int n  = g * 16 + (lane & 15);
    unsigned lo = f2bf(cls_w1[(size_t)kg * 256 + n]);
    unsigned hi = f2bf(cls_w1[(size_t)(kg + 1) * 256 + n]);
    *(unsigned*)(W1p + id) = lo | (hi << 16);
  }
  grid_bar(bar, (++gen) * 512u);

  // ---- P1: RB gemm (96 tiles) + qkv layer 0 (144 tiles) ----
  if (bid < 96) {
    int m0 = (bid % 24) * 64, n0 = (bid / 24) * 64;
    gemm_tile<0,0,0,1,0,0>(nullptr, 256, pair_rp, lut, cls_w1, cls_b1, RB,
                           nullptr, nullptr, nullptr, NDD, 256, 256, m0, n0, sm);
  } else if (bid < 240) {
    int u = bid - 96;
    int n0g = (u % 12) * 64, m0 = (u / 12) * 64;
    int bi = n0g >> 8, n0 = n0g & 255;
    const float* B = bi == 0 ? wq : (bi == 1 ? wk : wv);
    float* C = bi == 0 ? q : (bi == 1 ? k : v);
    gemm_tile<1,0,0,0,0,1>(x, 256, nullptr, nullptr, B, nullptr, C, nullptr,
                           ln1_s, ln1_b, LSEQ, 256, 256, m0, n0, sm);
  }
  grid_bar(bar, (++gen) * 512u);

  for (int l = 0; l < NLAYER; ++l) {
    const float* wo_l  = wo_ + (size_t)l * DM * DM;
    const float* ln2sl = ln2_s + l * DM;
    const float* ln2bl = ln2_b + l * DM;
    const float* fw1_l = ffn_w1 + (size_t)l * DM * DFF;
    const float* fb1_l = ffn_b1 + (size_t)l * DFF;
    const float* fw2_l = ffn_w2 + (size_t)l * DFF * DM;
    const float* fb2_l = ffn_b2 + (size_t)l * DM;

    // attn: 384 tasks, one per block
    if (bid < 384)
      attn_task(q, k, v, abias, o, (bid % 48) * 16, bid / 48, sm);
    grid_bar(bar, (++gen) * 512u);

    // wo split-K=2: x += o @ Wo  (96 tiles, atomicAdd)
    if (bid < 96) {
      int kc = bid / 48, v2 = bid % 48;
      int m0 = (v2 >> 2) * 64, n0 = (v2 & 3) * 64;
      gemm_tile<0,0,0,0,1,0>(o + kc * 128, 256, nullptr, nullptr,
                             wo_l + (size_t)(kc * 128) * 256, nullptr, x,
                             nullptr, nullptr, nullptr,
                             LSEQ, 128, 256, m0, n0, sm);
    }
    grid_bar(bar, (++gen) * 512u);

    // ffn1: f1 = gelu(LN2(x) @ fw1 + fb1)   (192 tiles)
    if (bid < 192) {
      int m0 = (bid >> 4) * 64, n0 = (bid & 15) * 64;
      gemm_tile<1,1,0,0,0,1>(x, 256, nullptr, nullptr, fw1_l, fb1_l, f1,
                             nullptr, ln2sl, ln2bl, LSEQ, 256, 1024, m0, n0, sm);
    }
    grid_bar(bar, (++gen) * 512u);

    // ffn2 split-K=4: x += f1 @ fw2 (+fb2 once)   (192 tiles, atomicAdd)
    if (bid < 192) {
      int kc = bid / 48, v2 = bid % 48;
      int m0 = (v2 >> 2) * 64, n0 = (v2 & 3) * 64;
      gemm_tile<0,0,0,0,1,0>(f1 + kc * 256, 1024, nullptr, nullptr,
                             fw2_l + (size_t)(kc * 256) * 256,
                             kc == 0 ? fb2_l : nullptr, x, nullptr,
                             nullptr, nullptr, LSEQ, 256, 256, m0, n0, sm);
    }
    grid_bar(bar, (++gen) * 512u);

    if (l < NLAYER - 1) {
      const float* wq_n = wq + (size_t)(l + 1) * DM * DM;
      const float* wk_n = wk + (size_t)(l + 1) * DM * DM;
      const float* wv_n = wv + (size_t)(l + 1) * DM * DM;
      const float* ln1sl = ln1_s + (l + 1) * DM;
      const float* ln1bl = ln1_b + (l + 1) * DM;
      if (bid < 144) {
        int n0g = (bid % 12) * 64, m0 = (bid / 12) * 64;
        int bi = n0g >> 8, n0 = n0g & 255;
        const float* B = bi == 0 ? wq_n : (bi == 1 ? wk_n : wv_n);
        float* C = bi == 0 ? q : (bi == 1 ? k : v);
        gemm_tile<1,0,0,0,0,1>(x, 256, nullptr, nullptr, B, nullptr, C, nullptr,
                               ln1sl, ln1bl, LSEQ, 256, 256, m0, n0, sm);
      }
      grid_bar(bar, (++gen) * 512u);
    } else {
      // pair projection (plain C: consumed by next dispatch)
      if (bid < 96) {
        int n0g = (bid % 8) * 64, m0 = (bid / 8) * 64;
        int bi = n0g >> 8, n0 = n0g & 255;
        const float* B = bi ? pair_k_w : pair_q_w;
        const float* bb = bi ? pair_k_b : pair_q_b;
        float* C = bi ? pk : pq;
        gemm_tile<1,0,0,0,0,0>(x, 256, nullptr, nullptr, B, bb, C, nullptr,
                               lnf_s, lnf_b, LSEQ, 256, 256, m0, n0, sm);
      }
    }
  }
}

// ---------------------------------------------------------------------------
// Fused pair head (unchanged).
#define PAIR_SMEM (36400 + 33792)

__global__ __launch_bounds__(256, 2) void k_pair(
    const float* __restrict__ pq, const float* __restrict__ pk,
    const unsigned short* __restrict__ W1p, const float* __restrict__ RB,
    const float* __restrict__ w2, const float* __restrict__ b2,
    float* __restrict__ out) {
  extern __shared__ char smem[];
  float* RB_s = (float*)smem;
  float* part = (float*)(smem + 36400);

  int t = threadIdx.x;
  int j0 = blockIdx.x * 32;
  int i0 = blockIdx.y * 4;
  int w = t >> 6, l = t & 63;
  int q4 = l >> 4, l15 = l & 15;
  int mwv = w & 1, nwv = w >> 1;

  {
    int ddmin = i0 - j0 + 736;
    for (int idx = t; idx < 35 * 64; idx += 256) {
      int lc = idx >> 6, c4 = (idx & 63) * 4;
      *(float4*)(RB_s + lc * 260 + c4) =
          *(const float4*)(RB + (size_t)(ddmin + lc) * 256 + c4);
    }
  }

  const float* q0p = pq + (size_t)(i0 + mwv * 2    ) * DM;
  const float* q1p = pq + (size_t)(i0 + mwv * 2 + 1) * DM;
  const float* k0p = pk + (size_t)(j0 + l15        ) * DM;
  const float* k1p = pk + (size_t)(j0 + 16 + l15   ) * DM;
  const unsigned short* Bp = W1p + (size_t)(nwv * 8) * 512 + (size_t)l * 8;

  f32x4 acc[4][8];
  #pragma unroll
  for (int a = 0; a < 4; ++a)
    #pragma unroll
    for (int b = 0; b < 8; ++b) acc[a][b] = (f32x4){0.f, 0.f, 0.f, 0.f};

  #pragma unroll 2
  for (int kc = 0; kc < 8; ++kc) {
    int c = kc * 32 + q4 * 8;
    float4 qa0 = *(const float4*)(q0p + c), qa1 = *(const float4*)(q0p + c + 4);
    float4 qb0 = *(const float4*)(q1p + c), qb1 = *(const float4*)(q1p + c + 4);
    float4 ka0 = *(const float4*)(k0p + c), ka1 = *(const float4*)(k0p + c + 4);
    float4 kb0 = *(const float4*)(k1p + c), kb1 = *(const float4*)(k1p + c + 4);

    bf16x8 bfv[8];
    const unsigned short* bb = Bp + (size_t)kc * 8192;
    #pragma unroll
    for (int nt = 0; nt < 8; ++nt)
      bfv[nt] = *(const bf16x8*)(bb + nt * 512);

    bf16x8 af[4];
    af[0][0]=(short)f2bf(qa0.x*ka0.x); af[0][1]=(short)f2bf(qa0.y*ka0.y);
    af[0][2]=(short)f2bf(qa0.z*ka0.z); af[0][3]=(short)f2bf(qa0.w*ka0.w);
    af[0][4]=(short)f2bf(qa1.x*ka1.x); af[0][5]=(short)f2bf(qa1.y*ka1.y);
    af[0][6]=(short)f2bf(qa1.z*ka1.z); af[0][7]=(short)f2bf(qa1.w*ka1.w);
    af[1][0]=(short)f2bf(qa0.x*kb0.x); af[1][1]=(short)f2bf(qa0.y*kb0.y);
    af[1][2]=(short)f2bf(qa0.z*kb0.z); af[1][3]=(short)f2bf(qa0.w*kb0.w);
    af[1][4]=(short)f2bf(qa1.x*kb1.x); af[1][5]=(short)f2bf(qa1.y*kb1.y);
    af[1][6]=(short)f2bf(qa1.z*kb1.z); af[1][7]=(short)f2bf(qa1.w*kb1.w);
    af[2][0]=(short)f2bf(qb0.x*ka0.x); af[2][1]=(short)f2bf(qb0.y*ka0.y);
    af[2][2]=(short)f2bf(qb0.z*ka0.z); af[2][3]=(short)f2bf(qb0.w*ka0.w);
    af[2][4]=(short)f2bf(qb1.x*ka1.x); af[2][5]=(short)f2bf(qb1.y*ka1.y);
    af[2][6]=(short)f2bf(qb1.z*ka1.z); af[2][7]=(short)f2bf(qb1.w*ka1.w);
    af[3][0]=(short)f2bf(qb0.x*kb0.x); af[3][1]=(short)f2bf(qb0.y*kb0.y);
    af[3][2]=(short)f2bf(qb0.z*kb0.z); af[3][3]=(short)f2bf(qb0.w*kb0.w);
    af[3][4]=(short)f2bf(qb1.x*kb1.x); af[3][5]=(short)f2bf(qb1.y*kb1.y);
    af[3][6]=(short)f2bf(qb1.z*kb1.z); af[3][7]=(short)f2bf(qb1.w*kb1.w);

    #pragma unroll
    for (int mt = 0; mt < 4; ++mt)
      #pragma unroll
      for (int nt = 0; nt < 8; ++nt)
        acc[mt][nt] = __builtin_amdgcn_mfma_f32_16x16x32_bf16(af[mt], bfv[nt], acc[mt][nt], 0, 0, 0);
  }

  __syncthreads();

  float w20[8], w21[8];
  #pragma unroll
  for (int nt = 0; nt < 8; ++nt) {
    int n = nwv * 128 + nt * 16 + l15;
    w20[nt] = w2[n * 2];
    w21[nt] = w2[n * 2 + 1];
  }
  #pragma unroll
  for (int mt = 0; mt < 4; ++mt) {
    #pragma unroll
    for (int reg = 0; reg < 4; ++reg) {
      int r = mwv * 64 + mt * 16 + q4 * 4 + reg;
      int lc = (r >> 5) - (r & 31) + 31;
      float o0 = 0.f, o1 = 0.f;
      #pragma unroll
      for (int nt = 0; nt < 8; ++nt) {
        int n = nwv * 128 + nt * 16 + l15;
        float T = acc[mt][nt][reg] + RB_s[lc * 260 + n];
        T = fmaxf(T, 0.f);
        o0 = fmaf(T, w20[nt], o0);
        o1 = fmaf(T, w21[nt], o1);
      }
      part[0 * 4224 + r * 33 + nwv * 16 + l15] = o0;
      part[1 * 4224 + r * 33 + nwv * 16 + l15] = o1;
    }
  }
  __syncthreads();
  {
    int r = t >> 1, oo = t & 1;
    float s = 0.f;
    #pragma unroll
    for (int c = 0; c < 32; ++c) s += part[oo * 4224 + r * 33 + c];
    out[((size_t)(i0 + (r >> 5)) * LSEQ + (j0 + (r & 31))) * 2 + oo] = s + b2[oo];
  }
}

// ---------------------------------------------------------------------------
extern "C" void kernel_launch(void* const* d_in, const int* in_sizes, int n_in,
                              void* d_out, int out_size, void* d_ws, size_t ws_size,
                              hipStream_t stream) {
  const int*   seq      = (const int*)  d_in[0];
  const float* tok_emb  = (const float*)d_in[1];
  const float* rp_emb   = (const float*)d_in[2];
  const float* wq       = (const float*)d_in[3];
  const float* wk       = (const float*)d_in[4];
  const float* wv       = (const float*)d_in[5];
  const float* wo       = (const float*)d_in[6];
  const float* ln1_s    = (const float*)d_in[7];
  const float* ln1_b    = (const float*)d_in[8];
  const float* ln2_s    = (const float*)d_in[9];
  const float* ln2_b    = (const float*)d_in[10];
  const float* ffn_w1   = (const float*)d_in[11];
  const float* ffn_b1   = (const float*)d_in[12];
  const float* ffn_w2   = (const float*)d_in[13];
  const float* ffn_b2   = (const float*)d_in[14];
  const float* lnf_s    = (const float*)d_in[15];
  const float* lnf_b    = (const float*)d_in[16];
  const float* pair_q_w = (const float*)d_in[17];
  const float* pair_q_b = (const float*)d_in[18];
  const float* pair_k_w = (const float*)d_in[19];
  const float* pair_k_b = (const float*)d_in[20];
  const float* pair_rp  = (const float*)d_in[21];
  const float* cls_w1   = (const float*)d_in[22];
  const float* cls_b1   = (const float*)d_in[23];
  const float* cls_w2   = (const float*)d_in[24];
  const float* cls_b2   = (const float*)d_in[25];
  float* out = (float*)d_out;

  char* ws = (char*)d_ws;
  float* x   = (float*)(ws + 0);
  float* q   = (float*)(ws + 786432);
  float* k   = (float*)(ws + 1572864);
  float* v   = (float*)(ws + 2359296);
  float* o   = (float*)(ws + 3145728);
  float* f1  = (float*)(ws + 3932160);
  float* pq  = (float*)(ws + 7077888);
  float* pk  = (float*)(ws + 7864320);
  float* RB  = (float*)(ws + 8650752);
  unsigned short* W1p = (unsigned short*)(ws + 10223616);
  int*   lut   = (int*)  (ws + 10354688);
  float* abias = (float*)(ws + 10360832);
  unsigned int* bar = (unsigned int*)(ws + 10410240);

  (void)in_sizes; (void)n_in; (void)out_size; (void)ws_size;

  hipFuncSetAttribute(reinterpret_cast<const void*>(k_pair),
                      hipFuncAttributeMaxDynamicSharedMemorySize, PAIR_SMEM);

  hipMemsetAsync((void*)bar, 0, 256, stream);

  k_stack<<<512, 256, 0, stream>>>(
      seq, tok_emb, rp_emb, wq, wk, wv, wo,
      ln1_s, ln1_b, ln2_s, ln2_b, ffn_w1, ffn_b1, ffn_w2, ffn_b2,
      lnf_s, lnf_b, pair_q_w, pair_q_b, pair_k_w, pair_k_b,
      pair_rp, cls_w1, cls_b1,
      x, q, k, v, o, f1, pq, pk, RB, W1p, lut, abias, bar);

  k_pair<<<dim3(24, 192), 256, PAIR_SMEM, stream>>>(pq, pk, W1p, RB, cls_w2, cls_b2, out);
}

// Round 5
// 2508.496 us; speedup vs baseline: 1.5413x; 1.5413x over previous
//
#include <hip/hip_runtime.h>
#include <hip/hip_bf16.h>
#include <stdint.h>

// ---------------------------------------------------------------------------
#define LSEQ 768
#define DM   256
#define NH   8
#define DK   32
#define DFF  1024
#define NLAYER 8
#define NDD  1535
// ---------------------------------------------------------------------------

typedef __attribute__((ext_vector_type(8))) short  bf16x8;
typedef __attribute__((ext_vector_type(4))) float  f32x4;

__device__ __forceinline__ unsigned short f2bf(float f) {
  unsigned u = __float_as_uint(f);
  u += 0x7fffu + ((u >> 16) & 1u);       // RNE
  return (unsigned short)(u >> 16);
}
__device__ __forceinline__ unsigned pk2(float a, float b) {
  __hip_bfloat162 h = __float22bfloat162_rn(make_float2(a, b));  // RNE, packed
  union { __hip_bfloat162 h; unsigned u; } c; c.h = h;
  return c.u;
}

// Agent-scope (L3-coherent) 8B ops — for tensors produced+consumed within one
// dispatch across XCDs. Validated correct on this HW in round 4.
__device__ __forceinline__ float2 ld2(const float* p) {
  union { unsigned long long u; float2 f; } c;
  c.u = __hip_atomic_load((unsigned long long*)(uintptr_t)p,
                          __ATOMIC_RELAXED, __HIP_MEMORY_SCOPE_AGENT);
  return c.f;
}
__device__ __forceinline__ void st2(float* p, float2 f) {
  union { float2 f; unsigned long long u; } c; c.f = f;
  __hip_atomic_store((unsigned long long*)p, c.u,
                     __ATOMIC_RELAXED, __HIP_MEMORY_SCOPE_AGENT);
}
__device__ __forceinline__ float4 ld4a(const float* p) {
  float2 a = ld2(p), b = ld2(p + 2);
  return make_float4(a.x, a.y, b.x, b.y);
}
__device__ __forceinline__ void st4a(float* p, float4 v) {
  st2(p, make_float2(v.x, v.y));
  st2(p + 2, make_float2(v.z, v.w));
}

// Flag protocol: producer stores (sc1/atomic, vmcnt-drained by __syncthreads)
// then one lane increments; consumer spins then __syncthreads. No fences.
__device__ __forceinline__ void sigc(unsigned* c) {
  __syncthreads();
  if (threadIdx.x == 0)
    __hip_atomic_fetch_add(c, 1u, __ATOMIC_RELAXED, __HIP_MEMORY_SCOPE_AGENT);
}
__device__ __forceinline__ void waitc(unsigned* c, unsigned tgt) {
  if (threadIdx.x == 0) {
    while (__hip_atomic_load(c, __ATOMIC_RELAXED, __HIP_MEMORY_SCOPE_AGENT) < tgt)
      __builtin_amdgcn_s_sleep(1);
  }
  __syncthreads();
}

__device__ __forceinline__ int bucket_of(int dd) {
  int rel = dd - 767;
  int ret = rel < 0 ? 32 : 0;
  int arp = rel < 0 ? -rel : rel;
  if (arp < 16) return ret + arp;
  const float lr = 2.772588722239781f;   // float(np.log(16))
  float val = logf((float)arp * 0.0625f) / lr * 16.0f;
  int vi = 16 + (int)val;
  return ret + (vi < 31 ? vi : 31);
}

// ---------------------------------------------------------------------------
// GEMM tile: 64x64, BK=32, register-prefetch double-buffered LDS.
// GR: 0 none, 1 = seq-gather from gsrc, 2 = inline-bucket gather from gsrc.
// ACOH: A (and res? no — res always plain) loads via agent-8B.
// CMODE via ATOMIC/CCOH. LDS need: 37376 bytes from smc.
template <int LN, int GELU, int RES, int GR, int ATOMIC, int ACOH, int CCOH>
__device__ void gemm_tile(const float* A, int lda,
                          const float* gsrc, const int* seqIdx,
                          const float* B, const float* bias, float* C,
                          const float* res, const float* lns, const float* lnb,
                          int M, int K, int N, int m0, int n0, char* smc) {
  float (*As)[32][68] = (float (*)[32][68])smc;
  float (*Bs)[32][68] = (float (*)[32][68])(smc + 17408);
  float (*stat)[2]    = (float (*)[2])(smc + 34816);
  float (*red)[8]     = (float (*)[8])(smc + 35328);

  int t = threadIdx.x;
  int arow = t >> 2, akq = (t & 3) * 8;
  int mg = m0 + arow;
  int mgc = mg < M ? mg : M - 1;
  const float* Ar;
  if (GR == 1)      Ar = gsrc + (size_t)seqIdx[mgc] * K;
  else if (GR == 2) Ar = gsrc + (size_t)bucket_of(mgc) * K;
  else              Ar = A + (size_t)mgc * lda;

  float mean = 0.f, rstd = 0.f;
  if (LN) {
    int lq = t & 3;
    float s = 0.f, s2 = 0.f;
    const float* p = Ar + lq * 64;
    #pragma unroll
    for (int c = 0; c < 64; c += 4) {
      float4 v = ACOH ? ld4a(p + c) : *(const float4*)(p + c);
      s  += v.x + v.y + v.z + v.w;
      s2 += v.x * v.x + v.y * v.y + v.z * v.z + v.w * v.w;
    }
    red[arow][lq] = s; red[arow][lq + 4] = s2;
    __syncthreads();
    if (lq == 0) {
      float sm = red[arow][0] + red[arow][1] + red[arow][2] + red[arow][3];
      float sq = red[arow][4] + red[arow][5] + red[arow][6] + red[arow][7];
      float m = sm * (1.f / 256.f);
      float v = sq * (1.f / 256.f) - m * m;
      stat[arow][0] = m;
      stat[arow][1] = rsqrtf(v + 1e-5f);
    }
    __syncthreads();
    mean = stat[arow][0]; rstd = stat[arow][1];
  }

  int bkr = t >> 3, bn8 = (t & 7) * 8;
  int ty = t >> 4, tx = t & 15;
  float acc[4][4] = {};
  int nk = K >> 5;
  float4 a0, a1, b0, b1;

  {
    a0 = ACOH ? ld4a(Ar + akq)     : *(const float4*)(Ar + akq);
    a1 = ACOH ? ld4a(Ar + akq + 4) : *(const float4*)(Ar + akq + 4);
    if (LN) {
      float4 ls0 = *(const float4*)(lns + akq), ls1 = *(const float4*)(lns + akq + 4);
      float4 lb0 = *(const float4*)(lnb + akq), lb1 = *(const float4*)(lnb + akq + 4);
      a0.x=(a0.x-mean)*rstd*ls0.x+lb0.x; a0.y=(a0.y-mean)*rstd*ls0.y+lb0.y;
      a0.z=(a0.z-mean)*rstd*ls0.z+lb0.z; a0.w=(a0.w-mean)*rstd*ls0.w+lb0.w;
      a1.x=(a1.x-mean)*rstd*ls1.x+lb1.x; a1.y=(a1.y-mean)*rstd*ls1.y+lb1.y;
      a1.z=(a1.z-mean)*rstd*ls1.z+lb1.z; a1.w=(a1.w-mean)*rstd*ls1.w+lb1.w;
    }
    b0 = *(const float4*)(B + (size_t)bkr * N + n0 + bn8);
    b1 = *(const float4*)(B + (size_t)bkr * N + n0 + bn8 + 4);
    As[0][akq+0][arow]=a0.x; As[0][akq+1][arow]=a0.y; As[0][akq+2][arow]=a0.z; As[0][akq+3][arow]=a0.w;
    As[0][akq+4][arow]=a1.x; As[0][akq+5][arow]=a1.y; As[0][akq+6][arow]=a1.z; As[0][akq+7][arow]=a1.w;
    *(float4*)&Bs[0][bkr][bn8] = b0;
    *(float4*)&Bs[0][bkr][bn8+4] = b1;
  }
  __syncthreads();

  for (int kt = 0; kt < nk; ++kt) {
    int cur = kt & 1;
    if (kt + 1 < nk) {
      int k0 = (kt + 1) << 5;
      a0 = ACOH ? ld4a(Ar + k0 + akq)     : *(const float4*)(Ar + k0 + akq);
      a1 = ACOH ? ld4a(Ar + k0 + akq + 4) : *(const float4*)(Ar + k0 + akq + 4);
      if (LN) {
        float4 ls0 = *(const float4*)(lns + k0 + akq), ls1 = *(const float4*)(lns + k0 + akq + 4);
        float4 lb0 = *(const float4*)(lnb + k0 + akq), lb1 = *(const float4*)(lnb + k0 + akq + 4);
        a0.x=(a0.x-mean)*rstd*ls0.x+lb0.x; a0.y=(a0.y-mean)*rstd*ls0.y+lb0.y;
        a0.z=(a0.z-mean)*rstd*ls0.z+lb0.z; a0.w=(a0.w-mean)*rstd*ls0.w+lb0.w;
        a1.x=(a1.x-mean)*rstd*ls1.x+lb1.x; a1.y=(a1.y-mean)*rstd*ls1.y+lb1.y;
        a1.z=(a1.z-mean)*rstd*ls1.z+lb1.z; a1.w=(a1.w-mean)*rstd*ls1.w+lb1.w;
      }
      b0 = *(const float4*)(B + (size_t)(k0 + bkr) * N + n0 + bn8);
      b1 = *(const float4*)(B + (size_t)(k0 + bkr) * N + n0 + bn8 + 4);
    }
    #pragma unroll
    for (int kk = 0; kk < 32; ++kk) {
      float4 a = *(float4*)&As[cur][kk][ty * 4];
      float4 b = *(float4*)&Bs[cur][kk][tx * 4];
      acc[0][0]=fmaf(a.x,b.x,acc[0][0]); acc[0][1]=fmaf(a.x,b.y,acc[0][1]);
      acc[0][2]=fmaf(a.x,b.z,acc[0][2]); acc[0][3]=fmaf(a.x,b.w,acc[0][3]);
      acc[1][0]=fmaf(a.y,b.x,acc[1][0]); acc[1][1]=fmaf(a.y,b.y,acc[1][1]);
      acc[1][2]=fmaf(a.y,b.z,acc[1][2]); acc[1][3]=fmaf(a.y,b.w,acc[1][3]);
      acc[2][0]=fmaf(a.z,b.x,acc[2][0]); acc[2][1]=fmaf(a.z,b.y,acc[2][1]);
      acc[2][2]=fmaf(a.z,b.z,acc[2][2]); acc[2][3]=fmaf(a.z,b.w,acc[2][3]);
      acc[3][0]=fmaf(a.w,b.x,acc[3][0]); acc[3][1]=fmaf(a.w,b.y,acc[3][1]);
      acc[3][2]=fmaf(a.w,b.z,acc[3][2]); acc[3][3]=fmaf(a.w,b.w,acc[3][3]);
    }
    if (kt + 1 < nk) {
      int nxt = cur ^ 1;
      As[nxt][akq+0][arow]=a0.x; As[nxt][akq+1][arow]=a0.y; As[nxt][akq+2][arow]=a0.z; As[nxt][akq+3][arow]=a0.w;
      As[nxt][akq+4][arow]=a1.x; As[nxt][akq+5][arow]=a1.y; As[nxt][akq+6][arow]=a1.z; As[nxt][akq+7][arow]=a1.w;
      *(float4*)&Bs[nxt][bkr][bn8] = b0;
      *(float4*)&Bs[nxt][bkr][bn8+4] = b1;
    }
    __syncthreads();
  }

  #pragma unroll
  for (int u = 0; u < 4; ++u) {
    int m = m0 + ty * 4 + u;
    if (m < M) {
      int n = n0 + tx * 4;
      float4 val = make_float4(acc[u][0], acc[u][1], acc[u][2], acc[u][3]);
      if (bias) {
        float4 bv = *(const float4*)(bias + n);
        val.x += bv.x; val.y += bv.y; val.z += bv.z; val.w += bv.w;
      }
      if (GELU) {
        val.x = 0.5f * val.x * (1.f + erff(val.x * 0.70710678118654752f));
        val.y = 0.5f * val.y * (1.f + erff(val.y * 0.70710678118654752f));
        val.z = 0.5f * val.z * (1.f + erff(val.z * 0.70710678118654752f));
        val.w = 0.5f * val.w * (1.f + erff(val.w * 0.70710678118654752f));
      }
      if (RES) {
        float4 r = *(const float4*)(res + (size_t)m * N + n);
        val.x += r.x; val.y += r.y; val.z += r.z; val.w += r.w;
      }
      if (ATOMIC) {
        atomicAdd(&C[(size_t)m * N + n + 0], val.x);
        atomicAdd(&C[(size_t)m * N + n + 1], val.y);
        atomicAdd(&C[(size_t)m * N + n + 2], val.z);
        atomicAdd(&C[(size_t)m * N + n + 3], val.w);
      } else if (CCOH) {
        st4a(C + (size_t)m * N + n, val);
      } else {
        *(float4*)(C + (size_t)m * N + n) = val;
      }
    }
  }
}

// ---------------------------------------------------------------------------
// Attention task: 16 query rows x 1 head. ALL inputs plain (cross-dispatch,
// L2-cached). Only the o store is agent-coherent (consumed within dispatch).
// LDS: S[16][776] @0 (49664), red @49664, mrow @50688, linv @50752,
// pr @50816 (9216) -> 60032 total.
__device__ void attn_task(const float* q, const float* k, const float* v,
                          const float* abias, float* o, int i0, int h, char* smc) {
  float* S = (float*)smc;
  float (*red)[16] = (float (*)[16])(smc + 49664);
  float* mrow = (float*)(smc + 50688);
  float* linv = (float*)(smc + 50752);
  float* pr   = (float*)(smc + 50816);

  int hc = h * DK;
  int t = threadIdx.x;
  int ti = t >> 4, tj = t & 15;

  float qr[32];
  {
    const float* qp = q + (size_t)(i0 + ti) * DM + hc;
    const float inv = 0.17677669529663687f;   // 1/sqrt(32)
    #pragma unroll
    for (int c = 0; c < 32; c += 4) {
      float4 v4 = *(const float4*)(qp + c);
      qr[c+0] = v4.x * inv; qr[c+1] = v4.y * inv;
      qr[c+2] = v4.z * inv; qr[c+3] = v4.w * inv;
    }
  }

  float mx = -1e30f;
  for (int jc = 0; jc < 48; ++jc) {
    int j = jc * 16 + tj;
    const float* kr = k + (size_t)j * DM + hc;
    float acc = 0.f;
    #pragma unroll
    for (int c = 0; c < 32; c += 4) {
      float4 kv = *(const float4*)(kr + c);
      acc = fmaf(qr[c+0], kv.x, acc);
      acc = fmaf(qr[c+1], kv.y, acc);
      acc = fmaf(qr[c+2], kv.z, acc);
      acc = fmaf(qr[c+3], kv.w, acc);
    }
    acc += abias[(size_t)(i0 + ti - j + 767) * 8 + h];
    S[ti * 776 + j] = acc;
    mx = fmaxf(mx, acc);
  }
  red[ti][tj] = mx;
  __syncthreads();
  if (tj == 0) {
    float m2 = red[ti][0];
    #pragma unroll
    for (int u = 1; u < 16; ++u) m2 = fmaxf(m2, red[ti][u]);
    mrow[ti] = m2;
  }
  __syncthreads();
  float m2 = mrow[ti];
  float sum = 0.f;
  for (int jc = 0; jc < 48; ++jc) {
    int j = jc * 16 + tj;
    float e = __expf(S[ti * 776 + j] - m2);
    S[ti * 776 + j] = e;
    sum += e;
  }
  red[ti][tj] = sum;
  __syncthreads();
  if (tj == 0) {
    float s2 = 0.f;
    #pragma unroll
    for (int u = 0; u < 16; ++u) s2 += red[ti][u];
    linv[ti] = 1.f / s2;
  }
  __syncthreads();

  {
    int wv = t >> 6, l = t & 63;
    int c4 = (l & 7) * 4;
    int ib = l >> 3;
    float a00=0,a01=0,a02=0,a03=0, a10=0,a11=0,a12=0,a13=0;
    const float* vp = v + hc + c4;
    int jbeg = wv * 192;
    for (int j = jbeg; j < jbeg + 192; j += 4) {
      float4 s0 = *(float4*)&S[ib * 776 + j];
      float4 s1 = *(float4*)&S[(ib + 8) * 776 + j];
      const float* vj = vp + (size_t)j * DM;
      float4 v0 = *(const float4*)(vj);
      float4 v1 = *(const float4*)(vj + DM);
      float4 v2 = *(const float4*)(vj + 2 * DM);
      float4 v3 = *(const float4*)(vj + 3 * DM);
      a00=fmaf(s0.x,v0.x,a00); a01=fmaf(s0.x,v0.y,a01); a02=fmaf(s0.x,v0.z,a02); a03=fmaf(s0.x,v0.w,a03);
      a10=fmaf(s1.x,v0.x,a10); a11=fmaf(s1.x,v0.y,a11); a12=fmaf(s1.x,v0.z,a12); a13=fmaf(s1.x,v0.w,a13);
      a00=fmaf(s0.y,v1.x,a00); a01=fmaf(s0.y,v1.y,a01); a02=fmaf(s0.y,v1.z,a02); a03=fmaf(s0.y,v1.w,a03);
      a10=fmaf(s1.y,v1.x,a10); a11=fmaf(s1.y,v1.y,a11); a12=fmaf(s1.y,v1.z,a12); a13=fmaf(s1.y,v1.w,a13);
      a00=fmaf(s0.z,v2.x,a00); a01=fmaf(s0.z,v2.y,a01); a02=fmaf(s0.z,v2.z,a02); a03=fmaf(s0.z,v2.w,a03);
      a10=fmaf(s1.z,v2.x,a10); a11=fmaf(s1.z,v2.y,a11); a12=fmaf(s1.z,v2.z,a12); a13=fmaf(s1.z,v2.w,a13);
      a00=fmaf(s0.w,v3.x,a00); a01=fmaf(s0.w,v3.y,a01); a02=fmaf(s0.w,v3.z,a02); a03=fmaf(s0.w,v3.w,a03);
      a10=fmaf(s1.w,v3.x,a10); a11=fmaf(s1.w,v3.y,a11); a12=fmaf(s1.w,v3.z,a12); a13=fmaf(s1.w,v3.w,a13);
    }
    pr[(ib * 4 + wv) * 36 + c4 + 0] = a00;
    pr[(ib * 4 + wv) * 36 + c4 + 1] = a01;
    pr[(ib * 4 + wv) * 36 + c4 + 2] = a02;
    pr[(ib * 4 + wv) * 36 + c4 + 3] = a03;
    pr[((ib + 8) * 4 + wv) * 36 + c4 + 0] = a10;
    pr[((ib + 8) * 4 + wv) * 36 + c4 + 1] = a11;
    pr[((ib + 8) * 4 + wv) * 36 + c4 + 2] = a12;
    pr[((ib + 8) * 4 + wv) * 36 + c4 + 3] = a13;
  }
  __syncthreads();
  {
    int idx = t * 2;
    int i = idx >> 5, c = idx & 31;
    float s0 = pr[(i*4+0)*36 + c] + pr[(i*4+1)*36 + c]
             + pr[(i*4+2)*36 + c] + pr[(i*4+3)*36 + c];
    float s1 = pr[(i*4+0)*36 + c+1] + pr[(i*4+1)*36 + c+1]
             + pr[(i*4+2)*36 + c+1] + pr[(i*4+3)*36 + c+1];
    st2(o + (size_t)(i0 + i) * DM + hc + c,
        make_float2(s0 * linv[i], s1 * linv[i]));
  }
}

// ---------------------------------------------------------------------------
// One transformer layer as ONE dispatch, stages pipelined by per-m-tile flags.
// grid=480, all co-resident (2 blocks/CU). Stage map:
//  A attn (384 tasks)     -> blocks 0..383, signal c_o[m] (tgt 32)
//  B wo+res (48 tiles)    -> blocks 384..431, wait c_o, signal c_x1[m] (tgt 4)
//  C ffn1 (192 tiles)     -> blocks 0..191 (2nd), wait c_x1, signal c_f1[m] (tgt 16)
//  D ffn2 splitK (192)    -> blocks 192..383 (2nd), wait c_f1, signal c_x2[m] (tgt 16)
//  E qkv_next/pair (144/96)-> blocks 384..479, wait c_x2
struct LArgs {
  const float *qin, *kin, *vin, *xin, *abias;
  float *qout, *kout, *vout, *xout, *o, *f1;
  const float *wo, *ln2s, *ln2b, *fw1, *fb1, *fw2, *fb2;
  const float *wnq, *wnk, *wnv, *lnns, *lnnb, *nqb, *nkb;
  unsigned* cnt;
  int last;
};

__global__ __launch_bounds__(256, 2) void k_layer(LArgs a) {
  __shared__ __align__(16) char sm[60032];
  int b = blockIdx.x;
  unsigned* c_o  = a.cnt;
  unsigned* c_x1 = a.cnt + 12;
  unsigned* c_f1 = a.cnt + 24;
  unsigned* c_x2 = a.cnt + 36;

  if (b < 384) {   // A: attention
    attn_task(a.qin, a.kin, a.vin, a.abias, a.o, (b % 48) * 16, b / 48, sm);
    sigc(&c_o[(b % 48) >> 2]);
  }
  if (b >= 384 && b < 432) {   // B: xout = xin + o@Wo
    int tb = b - 384, m = tb >> 2, n0 = (tb & 3) * 64;
    waitc(&c_o[m], 32);
    gemm_tile<0,0,1,0,0,1,1>(a.o, 256, nullptr, nullptr, a.wo, nullptr, a.xout,
                             a.xin, nullptr, nullptr, LSEQ, 256, 256, m * 64, n0, sm);
    sigc(&c_x1[m]);
  }
  if (b < 192) {   // C: f1 = gelu(LN2(xout)@fw1+fb1)
    int m = b >> 4, n0 = (b & 15) * 64;
    waitc(&c_x1[m], 4);
    gemm_tile<1,1,0,0,0,1,1>(a.xout, 256, nullptr, nullptr, a.fw1, a.fb1, a.f1,
                             nullptr, a.ln2s, a.ln2b, LSEQ, 256, 1024, m * 64, n0, sm);
    sigc(&c_f1[m]);
  }
  if (b >= 192 && b < 384) {   // D: xout += f1@fw2 (+fb2 once), split-K=4
    int td = b - 192, ks = td / 48, v2 = td % 48;
    int m = v2 >> 2, n0 = (v2 & 3) * 64;
    waitc(&c_f1[m], 16);
    gemm_tile<0,0,0,0,1,1,0>(a.f1 + ks * 256, 1024, nullptr, nullptr,
                             a.fw2 + (size_t)(ks * 256) * 256,
                             ks == 0 ? a.fb2 : nullptr, a.xout,
                             nullptr, nullptr, nullptr, LSEQ, 256, 256, m * 64, n0, sm);
    sigc(&c_x2[m]);
  }
  if (b >= 384) {   // E: qkv_next (144 tiles) or pair proj (96 tiles)
    int nE = a.last ? 96 : 144;
    for (int pass = 0; pass < 2; ++pass) {
      int te;
      if (pass == 0) te = b - 384;
      else { if (a.last || b < 432) break; te = 96 + (b - 432); }
      if (te >= nE) continue;
      if (!a.last) {
        int m = te / 12, ng = te % 12;
        int bi = ng >> 2, n0 = (ng & 3) * 64;
        const float* B = bi == 0 ? a.wnq : (bi == 1 ? a.wnk : a.wnv);
        float* C = bi == 0 ? a.qout : (bi == 1 ? a.kout : a.vout);
        waitc(&c_x2[m], 16);
        gemm_tile<1,0,0,0,0,1,0>(a.xout, 256, nullptr, nullptr, B, nullptr, C,
                                 nullptr, a.lnns, a.lnnb, LSEQ, 256, 256, m * 64, n0, sm);
      } else {
        int m = te >> 3, ng = te & 7;
        int bi = ng >> 2, n0 = (ng & 3) * 64;
        waitc(&c_x2[m], 16);
        gemm_tile<1,0,0,0,0,1,0>(a.xout, 256, nullptr, nullptr,
                                 bi ? a.wnk : a.wnq, bi ? a.nkb : a.nqb,
                                 bi ? a.kout : a.qout,
                                 nullptr, a.lnns, a.lnnb, LSEQ, 256, 256, m * 64, n0, sm);
      }
    }
  }
}

// ---------------------------------------------------------------------------
// Prep: RB gemm (inline bucket) + qkv layer0 (seq-gather+LN) + embed + abias
// + W1p pack. All blocks independent, one dispatch.
__global__ __launch_bounds__(256, 2) void k_prep(
    const int* __restrict__ seq, const float* __restrict__ tok_emb,
    const float* __restrict__ rp_emb,
    const float* __restrict__ wq0, const float* __restrict__ wk0,
    const float* __restrict__ wv0,
    const float* __restrict__ ln1s0, const float* __restrict__ ln1b0,
    const float* __restrict__ pair_rp, const float* __restrict__ cls_w1,
    const float* __restrict__ cls_b1,
    float* x0, float* q0, float* k0, float* v0, float* RB,
    unsigned short* W1p, float* abias) {
  __shared__ __align__(16) char sm[37376];
  int b = blockIdx.x, t = threadIdx.x;
  if (b < 96) {          // RB tiles: 24m x 4n
    int m0 = (b % 24) * 64, n0 = (b / 24) * 64;
    gemm_tile<0,0,0,2,0,0,0>(nullptr, 256, pair_rp, nullptr, cls_w1, cls_b1, RB,
                             nullptr, nullptr, nullptr, NDD, 256, 256, m0, n0, sm);
  } else if (b < 240) {  // qkv layer 0: gather tok_emb[seq] + LN1
    int u = b - 96;
    int n0g = (u % 12) * 64, m0 = (u / 12) * 64;
    int bi = n0g >> 8, n0 = n0g & 255;
    const float* B = bi == 0 ? wq0 : (bi == 1 ? wk0 : wv0);
    float* C = bi == 0 ? q0 : (bi == 1 ? k0 : v0);
    gemm_tile<1,0,0,1,0,0,0>(nullptr, 256, tok_emb, seq, B, nullptr, C,
                             nullptr, ln1s0, ln1b0, LSEQ, 256, 256, m0, n0, sm);
  } else if (b < 432) {  // embed x0: 4 rows per block
    int row = (b - 240) * 4 + (t >> 6), c = (t & 63) * 4;
    *(float4*)(x0 + (size_t)row * DM + c) =
        *(const float4*)(tok_emb + (size_t)seq[row] * DM + c);
  } else if (b < 438) {  // abias
    int dd = (b - 432) * 256 + t;
    if (dd < NDD) {
      int bk = bucket_of(dd);
      #pragma unroll
      for (int h = 0; h < NH; ++h) abias[dd * 8 + h] = rp_emb[bk * 8 + h];
    }
  } else {               // W1p fragment-order pack
    int base = (b - 438) * 1024 + t * 4;
    #pragma unroll
    for (int uu = 0; uu < 4; ++uu) {
      int id = base + uu;
      int e = id & 7, lane = (id >> 3) & 63, g = (id >> 9) & 15, kc = id >> 13;
      int kg = kc * 32 + (lane >> 4) * 8 + e;
      int n  = g * 16 + (lane & 15);
      W1p[id] = f2bf(cls_w1[(size_t)kg * 256 + n]);
    }
  }
}

// ---------------------------------------------------------------------------
// Fused pair head v3: q/k tiles staged in LDS (removes global latency from
// K-loop), W1p chunk prefetched one kc ahead, packed bf16 convert.
// LDS: qs[4][260] f32 @0 (4160), ks[32][260] @4160 (33280),
//      RB_s[35][260] @37440 (36400), racc[256] @73840 (1024) -> 74864.
#define PAIR_SMEM 74864

__global__ __launch_bounds__(256, 2) void k_pair(
    const float* __restrict__ pq, const float* __restrict__ pk,
    const unsigned short* __restrict__ W1p, const float* __restrict__ RB,
    const float* __restrict__ w2, const float* __restrict__ b2,
    float* __restrict__ out) {
  extern __shared__ char smem[];
  float* qs   = (float*)smem;
  float* ks   = (float*)(smem + 4160);
  float* RB_s = (float*)(smem + 37440);
  float* racc = (float*)(smem + 73840);

  int t = threadIdx.x;
  int j0 = blockIdx.x * 32;
  int i0 = blockIdx.y * 4;
  int w = t >> 6, l = t & 63;
  int q4 = l >> 4, l15 = l & 15;
  int mwv = w & 1, nwv = w >> 1;

  // ---- stage q (4 rows), k (32 rows), RB slice, zero racc ----
  {
    int row = t >> 6, c4 = (t & 63) * 4;
    *(float4*)(qs + row * 260 + c4) = *(const float4*)(pq + (size_t)(i0 + row) * DM + c4);
    #pragma unroll
    for (int r8 = 0; r8 < 8; ++r8) {
      int idx = t + r8 * 256;
      int kr = idx >> 6, kc4 = (idx & 63) * 4;
      *(float4*)(ks + kr * 260 + kc4) = *(const float4*)(pk + (size_t)(j0 + kr) * DM + kc4);
    }
    int ddmin = i0 - j0 + 736;
    for (int idx = t; idx < 35 * 64; idx += 256) {
      int lc = idx >> 6, c4b = (idx & 63) * 4;
      *(float4*)(RB_s + lc * 260 + c4b) =
          *(const float4*)(RB + (size_t)(ddmin + lc) * 256 + c4b);
    }
    racc[t] = 0.f;
  }
  __syncthreads();

  const unsigned short* Bp = W1p + (size_t)(nwv * 8) * 512 + (size_t)l * 8;
  const float* q0p = qs + (mwv * 2) * 260;
  const float* q1p = qs + (mwv * 2 + 1) * 260;
  const float* k0p = ks + l15 * 260;
  const float* k1p = ks + (16 + l15) * 260;

  f32x4 acc[4][8];
  #pragma unroll
  for (int aa = 0; aa < 4; ++aa)
    #pragma unroll
    for (int bb = 0; bb < 8; ++bb) acc[aa][bb] = (f32x4){0.f, 0.f, 0.f, 0.f};

  bf16x8 bcur[8];
  #pragma unroll
  for (int nt = 0; nt < 8; ++nt) bcur[nt] = *(const bf16x8*)(Bp + nt * 512);

  for (int kc = 0; kc < 8; ++kc) {
    bf16x8 bnxt[8];
    if (kc < 7) {
      const unsigned short* bbn = Bp + (size_t)(kc + 1) * 8192;
      #pragma unroll
      for (int nt = 0; nt < 8; ++nt) bnxt[nt] = *(const bf16x8*)(bbn + nt * 512);
    }
    int c = kc * 32 + q4 * 8;
    float4 qa0 = *(const float4*)(q0p + c), qa1 = *(const float4*)(q0p + c + 4);
    float4 qb0 = *(const float4*)(q1p + c), qb1 = *(const float4*)(q1p + c + 4);
    float4 ka0 = *(const float4*)(k0p + c), ka1 = *(const float4*)(k0p + c + 4);
    float4 kb0 = *(const float4*)(k1p + c), kb1 = *(const float4*)(k1p + c + 4);

    union { bf16x8 v; unsigned u[4]; } af[4];
    af[0].u[0] = pk2(qa0.x*ka0.x, qa0.y*ka0.y); af[0].u[1] = pk2(qa0.z*ka0.z, qa0.w*ka0.w);
    af[0].u[2] = pk2(qa1.x*ka1.x, qa1.y*ka1.y); af[0].u[3] = pk2(qa1.z*ka1.z, qa1.w*ka1.w);
    af[1].u[0] = pk2(qa0.x*kb0.x, qa0.y*kb0.y); af[1].u[1] = pk2(qa0.z*kb0.z, qa0.w*kb0.w);
    af[1].u[2] = pk2(qa1.x*kb1.x, qa1.y*kb1.y); af[1].u[3] = pk2(qa1.z*kb1.z, qa1.w*kb1.w);
    af[2].u[0] = pk2(qb0.x*ka0.x, qb0.y*ka0.y); af[2].u[1] = pk2(qb0.z*ka0.z, qb0.w*ka0.w);
    af[2].u[2] = pk2(qb1.x*ka1.x, qb1.y*ka1.y); af[2].u[3] = pk2(qb1.z*ka1.z, qb1.w*ka1.w);
    af[3].u[0] = pk2(qb0.x*kb0.x, qb0.y*kb0.y); af[3].u[1] = pk2(qb0.z*kb0.z, qb0.w*kb0.w);
    af[3].u[2] = pk2(qb1.x*kb1.x, qb1.y*kb1.y); af[3].u[3] = pk2(qb1.z*kb1.z, qb1.w*kb1.w);

    #pragma unroll
    for (int mt = 0; mt < 4; ++mt)
      #pragma unroll
      for (int nt = 0; nt < 8; ++nt)
        acc[mt][nt] = __builtin_amdgcn_mfma_f32_16x16x32_bf16(af[mt].v, bcur[nt], acc[mt][nt], 0, 0, 0);
    if (kc < 7) {
      #pragma unroll
      for (int nt = 0; nt < 8; ++nt) bcur[nt] = bnxt[nt];
    }
  }

  // ---- epilogue: +RB, relu, xW2, 16-lane shuffle reduce, LDS-atomic acc ----
  float w20[8], w21[8];
  #pragma unroll
  for (int nt = 0; nt < 8; ++nt) {
    int n = nwv * 128 + nt * 16 + l15;
    w20[nt] = w2[n * 2];
    w21[nt] = w2[n * 2 + 1];
  }
  #pragma unroll
  for (int mt = 0; mt < 4; ++mt) {
    #pragma unroll
    for (int reg = 0; reg < 4; ++reg) {
      int r = mwv * 64 + mt * 16 + q4 * 4 + reg;
      int lc = (r >> 5) - (r & 31) + 31;
      float o0 = 0.f, o1 = 0.f;
      #pragma unroll
      for (int nt = 0; nt < 8; ++nt) {
        int n = nwv * 128 + nt * 16 + l15;
        float T = acc[mt][nt][reg] + RB_s[lc * 260 + n];
        T = fmaxf(T, 0.f);
        o0 = fmaf(T, w20[nt], o0);
        o1 = fmaf(T, w21[nt], o1);
      }
      #pragma unroll
      for (int s = 1; s < 16; s <<= 1) {
        o0 += __shfl_xor(o0, s);
        o1 += __shfl_xor(o1, s);
      }
      if (l15 == 0) {
        atomicAdd(&racc[r * 2 + 0], o0);
        atomicAdd(&racc[r * 2 + 1], o1);
      }
    }
  }
  __syncthreads();
  {
    int r = t >> 1, oo = t & 1;
    out[((size_t)(i0 + (r >> 5)) * LSEQ + (j0 + (r & 31))) * 2 + oo] = racc[t] + b2[oo];
  }
}

// ---------------------------------------------------------------------------
extern "C" void kernel_launch(void* const* d_in, const int* in_sizes, int n_in,
                              void* d_out, int out_size, void* d_ws, size_t ws_size,
                              hipStream_t stream) {
  const int*   seq      = (const int*)  d_in[0];
  const float* tok_emb  = (const float*)d_in[1];
  const float* rp_emb   = (const float*)d_in[2];
  const float* wq       = (const float*)d_in[3];
  const float* wk       = (const float*)d_in[4];
  const float* wv       = (const float*)d_in[5];
  const float* wo       = (const float*)d_in[6];
  const float* ln1_s    = (const float*)d_in[7];
  const float* ln1_b    = (const float*)d_in[8];
  const float* ln2_s    = (const float*)d_in[9];
  const float* ln2_b    = (const float*)d_in[10];
  const float* ffn_w1   = (const float*)d_in[11];
  const float* ffn_b1   = (const float*)d_in[12];
  const float* ffn_w2   = (const float*)d_in[13];
  const float* ffn_b2   = (const float*)d_in[14];
  const float* lnf_s    = (const float*)d_in[15];
  const float* lnf_b    = (const float*)d_in[16];
  const float* pair_q_w = (const float*)d_in[17];
  const float* pair_q_b = (const float*)d_in[18];
  const float* pair_k_w = (const float*)d_in[19];
  const float* pair_k_b = (const float*)d_in[20];
  const float* pair_rp  = (const float*)d_in[21];
  const float* cls_w1   = (const float*)d_in[22];
  const float* cls_b1   = (const float*)d_in[23];
  const float* cls_w2   = (const float*)d_in[24];
  const float* cls_b2   = (const float*)d_in[25];
  float* out = (float*)d_out;

  char* ws = (char*)d_ws;
  float* xb0 = (float*)(ws + 0);
  float* xb1 = (float*)(ws + 786432);
  float* qb[2] = { (float*)(ws + 1572864), (float*)(ws + 3932160) };
  float* kb[2] = { (float*)(ws + 2359296), (float*)(ws + 4718592) };
  float* vb[2] = { (float*)(ws + 3145728), (float*)(ws + 5505024) };
  float* o   = (float*)(ws + 6291456);
  float* f1  = (float*)(ws + 7077888);
  float* pq  = (float*)(ws + 10223616);
  float* pk  = (float*)(ws + 11010048);
  float* RB  = (float*)(ws + 11796480);
  unsigned short* W1p = (unsigned short*)(ws + 13369344);
  float* abias = (float*)(ws + 13500416);
  unsigned* cnt = (unsigned*)(ws + 13549568);

  (void)in_sizes; (void)n_in; (void)out_size; (void)ws_size;

  hipFuncSetAttribute(reinterpret_cast<const void*>(k_pair),
                      hipFuncAttributeMaxDynamicSharedMemorySize, PAIR_SMEM);

  hipMemsetAsync((void*)cnt, 0, NLAYER * 64 * sizeof(unsigned), stream);

  k_prep<<<502, 256, 0, stream>>>(seq, tok_emb, rp_emb, wq, wk, wv,
                                  ln1_s, ln1_b, pair_rp, cls_w1, cls_b1,
                                  xb0, qb[0], kb[0], vb[0], RB, W1p, abias);

  for (int l = 0; l < NLAYER; ++l) {
    LArgs a{};
    int pi = l & 1, po = pi ^ 1;
    a.qin = qb[pi]; a.kin = kb[pi]; a.vin = vb[pi];
    a.xin = (l & 1) ? xb1 : xb0;
    a.xout = (l & 1) ? xb0 : xb1;
    a.abias = abias; a.o = o; a.f1 = f1;
    a.wo   = wo + (size_t)l * DM * DM;
    a.ln2s = ln2_s + l * DM; a.ln2b = ln2_b + l * DM;
    a.fw1 = ffn_w1 + (size_t)l * DM * DFF; a.fb1 = ffn_b1 + (size_t)l * DFF;
    a.fw2 = ffn_w2 + (size_t)l * DFF * DM; a.fb2 = ffn_b2 + (size_t)l * DM;
    a.cnt = cnt + l * 64;
    a.last = (l == NLAYER - 1);
    if (!a.last) {
      a.wnq = wq + (size_t)(l + 1) * DM * DM;
      a.wnk = wk + (size_t)(l + 1) * DM * DM;
      a.wnv = wv + (size_t)(l + 1) * DM * DM;
      a.lnns = ln1_s + (l + 1) * DM; a.lnnb = ln1_b + (l + 1) * DM;
      a.qout = qb[po]; a.kout = kb[po]; a.vout = vb[po];
      a.nqb = nullptr; a.nkb = nullptr;
    } else {
      a.wnq = pair_q_w; a.wnk = pair_k_w;
      a.wnv = nullptr;
      a.lnns = lnf_s; a.lnnb = lnf_b;
      a.qout = pq; a.kout = pk; a.vout = nullptr;
      a.nqb = pair_q_b; a.nkb = pair_k_b;
    }
    k_layer<<<480, 256, 0, stream>>>(a);
  }

  k_pair<<<dim3(24, 192), 256, PAIR_SMEM, stream>>>(pq, pk, W1p, RB, cls_w2, cls_b2, out);
}